// Round 5
// baseline (490.830 us; speedup 1.0000x reference)
//
#include <hip/hip_runtime.h>

typedef unsigned short u16;
typedef unsigned int u32;
typedef unsigned long long u64;
typedef __attribute__((ext_vector_type(8))) u16 u16x8;
typedef __attribute__((ext_vector_type(8))) __bf16 bf16x8;
typedef __attribute__((ext_vector_type(4))) float f32x4;

#define D_MODEL 1024
#define SEQ 2048
#define NBATCH 4
#define NHEAD 16
#define DKH 64

__device__ __forceinline__ u16 f2bf(float f) {
  u32 u = __builtin_bit_cast(u32, f);
  u += 0x7fffu + ((u >> 16) & 1u);   // RTNE
  return (u16)(u >> 16);
}
__device__ __forceinline__ float bf2f(u16 h) {
  u32 u = ((u32)h) << 16;
  return __builtin_bit_cast(float, u);
}
__device__ __forceinline__ f32x4 MFMA(u16x8 a, u16x8 b, f32x4 c) {
  return __builtin_amdgcn_mfma_f32_16x16x32_bf16(
      __builtin_bit_cast(bf16x8, a), __builtin_bit_cast(bf16x8, b), c, 0, 0, 0);
}

#define GLD16(gsrc, ldst)                                                     \
  __builtin_amdgcn_global_load_lds(                                           \
      (const __attribute__((address_space(1))) void*)(gsrc),                  \
      (__attribute__((address_space(3))) void*)(ldst), 16, 0, 0)

// ---------------------------------------------------------------------------
// fp32 -> bf16 conversion for x (8388608 elems) + Wq/Wk/Wv/Wo (1048576 each).
// ---------------------------------------------------------------------------
__global__ __launch_bounds__(256) void conv_all(
    const float* __restrict__ x, const float* __restrict__ wq,
    const float* __restrict__ wk, const float* __restrict__ wv,
    const float* __restrict__ wo, u16* __restrict__ xb, u16* __restrict__ wqb,
    u16* __restrict__ wkb, u16* __restrict__ wvb, u16* __restrict__ wob) {
  long qd = (long)blockIdx.x * 256 + threadIdx.x;
  long e = qd << 2;
  const float* src;
  u16* dst;
  long off;
  if (e < 8388608L) {
    src = x; dst = xb; off = e;
  } else {
    long j = e - 8388608L;
    int w = (int)(j >> 20);
    off = j & 1048575L;
    src = (w == 0) ? wq : (w == 1) ? wk : (w == 2) ? wv : wo;
    dst = (w == 0) ? wqb : (w == 1) ? wkb : (w == 2) ? wvb : wob;
  }
  float4 v = *(const float4*)(src + off);
  u32 lo32 = (u32)f2bf(v.x) | ((u32)f2bf(v.y) << 16);
  u32 hi32 = (u32)f2bf(v.z) | ((u32)f2bf(v.w) << 16);
  *(u64*)(dst + off) = (u64)lo32 | ((u64)hi32 << 32);
}

// ---------------------------------------------------------------------------
// C[M][N] = A[M][K] * Bm[N][K]^T   (m97 structure, unchanged from R0)
// ---------------------------------------------------------------------------
template <int OUTF>
__global__ __launch_bounds__(256) void gemm_bt(
    const u16* __restrict__ A, const u16* __restrict__ Bm, u16* __restrict__ Cb,
    float* __restrict__ Cf, const float* __restrict__ bias, int M, int N,
    int K) {
  __shared__ u16 As[128 * 64];
  __shared__ u16 Bs[128 * 64];
  const int tid = threadIdx.x;
  const int lane = tid & 63, wave = tid >> 6;
  const int lo = lane & 15, g = lane >> 4;
  const int mBase = blockIdx.y * 128, nBase = blockIdx.x * 128;
  const int wr = wave >> 1, wc = wave & 1;

  f32x4 acc[4][4];
#pragma unroll
  for (int mi = 0; mi < 4; ++mi)
#pragma unroll
    for (int ni = 0; ni < 4; ++ni) acc[mi][ni] = (f32x4){0.f, 0.f, 0.f, 0.f};

  const int nK = K >> 6;
  for (int kb = 0; kb < nK; ++kb) {
    __syncthreads();
    const u16* Ab = A + (size_t)mBase * K + kb * 64;
    const u16* Bb = Bm + (size_t)nBase * K + kb * 64;
#pragma unroll
    for (int i = 0; i < 4; ++i) {
      int flat = (i * 256 + tid) * 8;
      int r = flat >> 6, c = flat & 63;
      GLD16(Ab + (size_t)r * K + c, As + (i * 256 + wave * 64) * 8);
    }
#pragma unroll
    for (int i = 0; i < 4; ++i) {
      int flat = (i * 256 + tid) * 8;
      int r = flat >> 6, c = flat & 63;
      GLD16(Bb + (size_t)r * K + c, Bs + (i * 256 + wave * 64) * 8);
    }
    __syncthreads();

#pragma unroll
    for (int kk = 0; kk < 64; kk += 32) {
      u16x8 a[4], b[4];
#pragma unroll
      for (int mi = 0; mi < 4; ++mi)
        a[mi] = *(const u16x8*)&As[(wr * 64 + mi * 16 + lo) * 64 + kk + g * 8];
#pragma unroll
      for (int ni = 0; ni < 4; ++ni)
        b[ni] = *(const u16x8*)&Bs[(wc * 64 + ni * 16 + lo) * 64 + kk + g * 8];
#pragma unroll
      for (int mi = 0; mi < 4; ++mi)
#pragma unroll
        for (int ni = 0; ni < 4; ++ni)
          acc[mi][ni] = MFMA(a[mi], b[ni], acc[mi][ni]);
    }
  }

#pragma unroll
  for (int mi = 0; mi < 4; ++mi)
#pragma unroll
    for (int ni = 0; ni < 4; ++ni) {
      int row0 = mBase + wr * 64 + mi * 16 + g * 4;
      int col = nBase + wc * 64 + ni * 16 + lo;
      float bv = 0.f;
      if constexpr (OUTF == 1) bv = bias[col];
#pragma unroll
      for (int r = 0; r < 4; ++r) {
        size_t idx = (size_t)(row0 + r) * N + col;
        if constexpr (OUTF == 0)
          Cb[idx] = f2bf(acc[mi][ni][r]);
        else
          Cf[idx] = acc[mi][ni][r] + bv;
      }
    }
}

// ---------------------------------------------------------------------------
// Flash attention v3: 2048 blocks (one 64-row q-tile each), LPT dispatch
// (longest tiles first), XCD-grouped (b,h).  NO setprio (was serializing
// waves: 16 independent waves/CU flipping prio starved each other's issue).
// V loads issued pre-softmax (covered by softmax latency).  K fragments
// register-prefetched one chunk ahead; mask word prefetched; no barriers.
// Q/K read from merged QK buffer (row stride 2048; K at col offset 1024).
// ---------------------------------------------------------------------------
__global__ __launch_bounds__(256, 4) void attn_fwd(
    const u16* __restrict__ QK, const u16* __restrict__ Vt,
    const int* __restrict__ mask, u16* __restrict__ ctx) {
  __shared__ u16 Plds[4][16 * 72];  // per-wave 16 rows x 144B stride
  // bid0 -> (xcd, group-in-xcd, tile): consecutive bid0 round-robin XCDs;
  // tz ascending => t=31-tz descending => longest blocks dispatch first (LPT).
  const int bid0 = blockIdx.x;
  const int xcd = bid0 & 7, gi = (bid0 >> 3) & 7, tz = bid0 >> 6;
  const int t = 31 - tz;                 // this block's q-tile, t+1 chunks
  const int gh = xcd * 8 + gi;           // (b,h) group 0..63
  const int h = gh & 15, b = gh >> 4;
  const int q0 = t << 6;
  const int tid = threadIdx.x;
  const int lane = tid & 63, wave = tid >> 6;
  const int lo = lane & 15, g = lane >> 4;
  char* P = (char*)&Plds[wave][0];

  const int qrow = q0 + wave * 16 + lo;  // this lane's q row (softmax owner)

  // Q fragment (B-operand): lane holds Q[q=lo][dk=g*8+j], x2 for dk 0..63.
  const size_t qoff = ((size_t)(b * SEQ + qrow)) * 2048 + h * DKH + g * 8;
  u16x8 bq0 = *(const u16x8*)(QK + qoff);
  u16x8 bq1 = *(const u16x8*)(QK + qoff + 32);
#pragma unroll
  for (int j = 0; j < 8; ++j) {  // fold 1/sqrt(Dk)=0.125 (exact exp shift)
    bq0[j] = (u16)(__builtin_bit_cast(u32, bf2f(bq0[j]) * 0.125f) >> 16);
    bq1[j] = (u16)(__builtin_bit_cast(u32, bf2f(bq1[j]) * 0.125f) >> 16);
  }

  float m = -1e9f, lsum = 0.f;
  f32x4 o[4];
#pragma unroll
  for (int dt = 0; dt < 4; ++dt) o[dt] = (f32x4){0.f, 0.f, 0.f, 0.f};

  // preload K chunk 0 (cols 1024.. of QK) and mask word chunk 0
  u16x8 ak0[4], ak1[4];
#pragma unroll
  for (int kt = 0; kt < 4; ++kt) {
    const u16* kp = QK + ((size_t)(b * SEQ + kt * 16 + lo)) * 2048 + 1024 +
                    h * DKH + g * 8;
    ak0[kt] = *(const u16x8*)kp;
    ak1[kt] = *(const u16x8*)(kp + 32);
  }
  int mv = mask[b * SEQ + lane];

#pragma unroll 1
  for (int c = 0; c <= t; ++c) {
    u64 bm = __ballot(mv != 0);

    // S^T tile: mfma(A=K, B=Q) -> D[key][q]; lane: col q=lo,
    // rows key = kt*16 + g*4 + r.
    f32x4 s[4];
#pragma unroll
    for (int kt = 0; kt < 4; ++kt) {
      f32x4 z = (f32x4){0.f, 0.f, 0.f, 0.f};
      s[kt] = MFMA(ak0[kt], bq0, z);
      s[kt] = MFMA(ak1[kt], bq1, s[kt]);
    }

    // prefetch K + mask for next chunk (clamped; regs free after S-MFMAs)
    const int cn = (c < t) ? c + 1 : t;
#pragma unroll
    for (int kt = 0; kt < 4; ++kt) {
      const u16* kp = QK +
                      ((size_t)(b * SEQ + (cn << 6) + kt * 16 + lo)) * 2048 +
                      1024 + h * DKH + g * 8;
      ak0[kt] = *(const u16x8*)kp;
      ak1[kt] = *(const u16x8*)(kp + 32);
    }
    // early-issue V for THIS chunk: covered by the whole softmax below
    u16x8 vv0[4], vv1[4];
#pragma unroll
    for (int dt = 0; dt < 4; ++dt) {
      const u16* vp = Vt + ((size_t)(h * DKH + dt * 16 + lo)) * (NBATCH * SEQ) +
                      b * SEQ + (c << 6) + g * 8;
      vv0[dt] = *(const u16x8*)vp;
      vv1[dt] = *(const u16x8*)(vp + 32);
    }
    mv = mask[b * SEQ + (cn << 6) + lane];

    if (bm != ~0ull || c == t) {
#pragma unroll
      for (int kt = 0; kt < 4; ++kt)
#pragma unroll
        for (int r = 0; r < 4; ++r) {
          int kl = kt * 16 + g * 4 + r;
          int kk = (c << 6) + kl;
          if ((kk > qrow) || (((bm >> kl) & 1ull) == 0)) s[kt][r] = -1e9f;
        }
    }

    // online softmax: lane owns q-row lo; 16 key-scores local (tree reduce)
    float c0 = fmaxf(fmaxf(s[0][0], s[0][1]), fmaxf(s[0][2], s[0][3]));
    float c1 = fmaxf(fmaxf(s[1][0], s[1][1]), fmaxf(s[1][2], s[1][3]));
    float c2 = fmaxf(fmaxf(s[2][0], s[2][1]), fmaxf(s[2][2], s[2][3]));
    float c3 = fmaxf(fmaxf(s[3][0], s[3][1]), fmaxf(s[3][2], s[3][3]));
    float cm = fmaxf(fmaxf(c0, c1), fmaxf(c2, c3));
    cm = fmaxf(cm, __shfl_xor(cm, 16));
    cm = fmaxf(cm, __shfl_xor(cm, 32));
    float mn = fmaxf(m, cm);
    float fsc = __expf(m - mn);
    m = mn;

    float rsk[4];
#pragma unroll
    for (int kt = 0; kt < 4; ++kt) {
      float p0 = __expf(s[kt][0] - mn);
      float p1 = __expf(s[kt][1] - mn);
      float p2 = __expf(s[kt][2] - mn);
      float p3 = __expf(s[kt][3] - mn);
      rsk[kt] = (p0 + p1) + (p2 + p3);
      // P[q=lo][key=kt*16+g*4..+3] as one ds_write_b64; 16B-chunk XOR
      // swizzle: physchunk = (key>>3) ^ (lo&7)
      u32 w0 = (u32)f2bf(p0) | ((u32)f2bf(p1) << 16);
      u32 w1 = (u32)f2bf(p2) | ((u32)f2bf(p3) << 16);
      int key = kt * 16 + g * 4;
      int byteoff =
          lo * 144 + ((((key >> 3) ^ (lo & 7)) << 4) | ((key & 7) << 1));
      *(u64*)(P + byteoff) = (u64)w0 | ((u64)w1 << 32);
    }
    float rs = (rsk[0] + rsk[1]) + (rsk[2] + rsk[3]);
    rs += __shfl_xor(rs, 16);
    rs += __shfl_xor(rs, 32);
    lsum = lsum * fsc + rs;

    // rescale O rows (row index of o regs = g*4+r; fsc lives at lane==row)
#pragma unroll
    for (int r = 0; r < 4; ++r) {
      float fr = __shfl(fsc, (g << 2) + r);
      o[0][r] *= fr;
      o[1][r] *= fr;
      o[2][r] *= fr;
      o[3][r] *= fr;
    }

    // PV: A = P (lane: row q=lo, key=g*8+j / 32+g*8+j), B = V (early-issued)
    u16x8 ap0 = *(const u16x8*)(P + lo * 144 + ((g ^ (lo & 7)) << 4));
    u16x8 ap1 = *(const u16x8*)(P + lo * 144 + (((4 + g) ^ (lo & 7)) << 4));
#pragma unroll
    for (int dt = 0; dt < 4; ++dt) {
      o[dt] = MFMA(ap0, vv0[dt], o[dt]);
      o[dt] = MFMA(ap1, vv1[dt], o[dt]);
    }
  }

  // finalize: divide rows by lsum (held at lane==row), store bf16 ctx
#pragma unroll
  for (int r = 0; r < 4; ++r) {
    float lr = __shfl(lsum, (g << 2) + r);
    float inv = 1.f / lr;
    int row = q0 + wave * 16 + (g << 2) + r;
#pragma unroll
    for (int dt = 0; dt < 4; ++dt) {
      int col = h * DKH + dt * 16 + lo;
      ctx[((size_t)(b * SEQ + row)) * D_MODEL + col] = f2bf(o[dt][r] * inv);
    }
  }
}

// ---------------------------------------------------------------------------
extern "C" void kernel_launch(void* const* d_in, const int* in_sizes, int n_in,
                              void* d_out, int out_size, void* d_ws,
                              size_t ws_size, hipStream_t stream) {
  const float* x = (const float*)d_in[0];
  const int* mask = (const int*)d_in[1];
  const float* Wq = (const float*)d_in[2];
  const float* Wk = (const float*)d_in[3];
  const float* Wv = (const float*)d_in[4];
  const float* Wo = (const float*)d_in[5];
  const float* bo = (const float*)d_in[6];
  float* out = (float*)d_out;

  // workspace layout (bf16 elements); total 46137344 elems = 88 MiB
  u16* xb = (u16*)d_ws;          // 8388608
  u16* wqb = xb + 8388608;       // 1048576 (wkb follows contiguously ->
  u16* wkb = wqb + 1048576;      //  wqb is also the [2048][1024] QK weight)
  u16* wvb = wkb + 1048576;
  u16* wob = wvb + 1048576;
  u16* QKm = wob + 1048576;      // 16777216: [8192][2048], Q cols 0..1023,
                                 //  K cols 1024..2047
  u16* Vt = QKm + 16777216;      // 8388608 (layout: [1024 e][8192 b*S+s])
  u16* ctx = Vt + 8388608;       // 8388608
  if (ws_size < (size_t)46137344 * 2) return;

  conv_all<<<12288, 256, 0, stream>>>(x, Wq, Wk, Wv, Wo, xb, wqb, wkb, wvb, wob);

  // [Q|K] = x [Wq;Wk]^T : (8192x2048), one merged GEMM (weights contiguous)
  gemm_bt<0><<<dim3(16, 64), 256, 0, stream>>>(xb, wqb, QKm, nullptr, nullptr,
                                               8192, 2048, 1024);
  // V^T = Wv x^T : (1024x8192)  -- free transpose via operand swap
  gemm_bt<0><<<dim3(64, 8), 256, 0, stream>>>(wvb, xb, Vt, nullptr, nullptr,
                                              1024, 8192, 1024);

  attn_fwd<<<2048, 256, 0, stream>>>(QKm, Vt, mask, ctx);

  // out = ctx Wo^T + bo : fp32
  gemm_bt<1><<<dim3(8, 64), 256, 0, stream>>>(ctx, wob, nullptr, out, bo, 8192,
                                              1024, 1024);
}

// Round 9
// 453.041 us; speedup vs baseline: 1.0834x; 1.0834x over previous
//
#include <hip/hip_runtime.h>

typedef unsigned short u16;
typedef unsigned int u32;
typedef unsigned long long u64;
typedef __attribute__((ext_vector_type(8))) u16 u16x8;
typedef __attribute__((ext_vector_type(8))) __bf16 bf16x8;
typedef __attribute__((ext_vector_type(4))) float f32x4;

#define D_MODEL 1024
#define SEQ 2048
#define NBATCH 4
#define NHEAD 16
#define DKH 64

__device__ __forceinline__ u16 f2bf(float f) {
  u32 u = __builtin_bit_cast(u32, f);
  u += 0x7fffu + ((u >> 16) & 1u);   // RTNE
  return (u16)(u >> 16);
}
__device__ __forceinline__ float bf2f(u16 h) {
  u32 u = ((u32)h) << 16;
  return __builtin_bit_cast(float, u);
}
__device__ __forceinline__ f32x4 MFMA(u16x8 a, u16x8 b, f32x4 c) {
  return __builtin_amdgcn_mfma_f32_16x16x32_bf16(
      __builtin_bit_cast(bf16x8, a), __builtin_bit_cast(bf16x8, b), c, 0, 0, 0);
}

#define GLD16(gsrc, ldst)                                                     \
  __builtin_amdgcn_global_load_lds(                                           \
      (const __attribute__((address_space(1))) void*)(gsrc),                  \
      (__attribute__((address_space(3))) void*)(ldst), 16, 0, 0)

// ---------------------------------------------------------------------------
// fp32 -> bf16 conversion for x (8388608 elems) + Wq/Wk/Wv/Wo (1048576 each).
// ---------------------------------------------------------------------------
__global__ __launch_bounds__(256) void conv_all(
    const float* __restrict__ x, const float* __restrict__ wq,
    const float* __restrict__ wk, const float* __restrict__ wv,
    const float* __restrict__ wo, u16* __restrict__ xb, u16* __restrict__ wqb,
    u16* __restrict__ wkb, u16* __restrict__ wvb, u16* __restrict__ wob) {
  long qd = (long)blockIdx.x * 256 + threadIdx.x;
  long e = qd << 2;
  const float* src;
  u16* dst;
  long off;
  if (e < 8388608L) {
    src = x; dst = xb; off = e;
  } else {
    long j = e - 8388608L;
    int w = (int)(j >> 20);
    off = j & 1048575L;
    src = (w == 0) ? wq : (w == 1) ? wk : (w == 2) ? wv : wo;
    dst = (w == 0) ? wqb : (w == 1) ? wkb : (w == 2) ? wvb : wob;
  }
  float4 v = *(const float4*)(src + off);
  u32 lo32 = (u32)f2bf(v.x) | ((u32)f2bf(v.y) << 16);
  u32 hi32 = (u32)f2bf(v.z) | ((u32)f2bf(v.w) << 16);
  *(u64*)(dst + off) = (u64)lo32 | ((u64)hi32 << 32);
}

// ---------------------------------------------------------------------------
// C[M][N] = A[M][K] * Bm[N][K]^T   (m97 structure, unchanged)
// ---------------------------------------------------------------------------
template <int OUTF>
__global__ __launch_bounds__(256) void gemm_bt(
    const u16* __restrict__ A, const u16* __restrict__ Bm, u16* __restrict__ Cb,
    float* __restrict__ Cf, const float* __restrict__ bias, int M, int N,
    int K) {
  __shared__ u16 As[128 * 64];
  __shared__ u16 Bs[128 * 64];
  const int tid = threadIdx.x;
  const int lane = tid & 63, wave = tid >> 6;
  const int lo = lane & 15, g = lane >> 4;
  const int mBase = blockIdx.y * 128, nBase = blockIdx.x * 128;
  const int wr = wave >> 1, wc = wave & 1;

  f32x4 acc[4][4];
#pragma unroll
  for (int mi = 0; mi < 4; ++mi)
#pragma unroll
    for (int ni = 0; ni < 4; ++ni) acc[mi][ni] = (f32x4){0.f, 0.f, 0.f, 0.f};

  const int nK = K >> 6;
  for (int kb = 0; kb < nK; ++kb) {
    __syncthreads();
    const u16* Ab = A + (size_t)mBase * K + kb * 64;
    const u16* Bb = Bm + (size_t)nBase * K + kb * 64;
#pragma unroll
    for (int i = 0; i < 4; ++i) {
      int flat = (i * 256 + tid) * 8;
      int r = flat >> 6, c = flat & 63;
      GLD16(Ab + (size_t)r * K + c, As + (i * 256 + wave * 64) * 8);
    }
#pragma unroll
    for (int i = 0; i < 4; ++i) {
      int flat = (i * 256 + tid) * 8;
      int r = flat >> 6, c = flat & 63;
      GLD16(Bb + (size_t)r * K + c, Bs + (i * 256 + wave * 64) * 8);
    }
    __syncthreads();

#pragma unroll
    for (int kk = 0; kk < 64; kk += 32) {
      u16x8 a[4], b[4];
#pragma unroll
      for (int mi = 0; mi < 4; ++mi)
        a[mi] = *(const u16x8*)&As[(wr * 64 + mi * 16 + lo) * 64 + kk + g * 8];
#pragma unroll
      for (int ni = 0; ni < 4; ++ni)
        b[ni] = *(const u16x8*)&Bs[(wc * 64 + ni * 16 + lo) * 64 + kk + g * 8];
#pragma unroll
      for (int mi = 0; mi < 4; ++mi)
#pragma unroll
        for (int ni = 0; ni < 4; ++ni)
          acc[mi][ni] = MFMA(a[mi], b[ni], acc[mi][ni]);
    }
  }

#pragma unroll
  for (int mi = 0; mi < 4; ++mi)
#pragma unroll
    for (int ni = 0; ni < 4; ++ni) {
      int row0 = mBase + wr * 64 + mi * 16 + g * 4;
      int col = nBase + wc * 64 + ni * 16 + lo;
      float bv = 0.f;
      if constexpr (OUTF == 1) bv = bias[col];
#pragma unroll
      for (int r = 0; r < 4; ++r) {
        size_t idx = (size_t)(row0 + r) * N + col;
        if constexpr (OUTF == 0)
          Cb[idx] = f2bf(acc[mi][ni][r]);
        else
          Cf[idx] = acc[mi][ni][r] + bv;
      }
    }
}

// ---------------------------------------------------------------------------
// Flash attention v4: v3's LPT grid + NO occupancy clamp.
// __launch_bounds__(256,4) in v2/v3 capped arch-VGPRs at 64 -> per-iteration
// scratch spills (WRITE_SIZE 58-106 MB vs 16.7 MB output, ~20k cy/iter).
// Plain (256) lets the allocator keep all state in registers (~110 VGPR).
// V issued after P-write (short reg lifetime, ~150cy latency cover).
// ---------------------------------------------------------------------------
__global__ __launch_bounds__(256) void attn_fwd(
    const u16* __restrict__ QK, const u16* __restrict__ Vt,
    const int* __restrict__ mask, u16* __restrict__ ctx) {
  __shared__ u16 Plds[4][16 * 72];  // per-wave 16 rows x 144B stride
  // bid0 -> (xcd, group-in-xcd, tile): consecutive bid0 round-robin XCDs;
  // tz ascending => t=31-tz descending => longest blocks dispatch first (LPT).
  const int bid0 = blockIdx.x;
  const int xcd = bid0 & 7, gi = (bid0 >> 3) & 7, tz = bid0 >> 6;
  const int t = 31 - tz;                 // this block's q-tile, t+1 chunks
  const int gh = xcd * 8 + gi;           // (b,h) group 0..63
  const int h = gh & 15, b = gh >> 4;
  const int q0 = t << 6;
  const int tid = threadIdx.x;
  const int lane = tid & 63, wave = tid >> 6;
  const int lo = lane & 15, g = lane >> 4;
  char* P = (char*)&Plds[wave][0];

  const int qrow = q0 + wave * 16 + lo;  // this lane's q row (softmax owner)

  // Q fragment (B-operand): lane holds Q[q=lo][dk=g*8+j], x2 for dk 0..63.
  const size_t qoff = ((size_t)(b * SEQ + qrow)) * 2048 + h * DKH + g * 8;
  u16x8 bq0 = *(const u16x8*)(QK + qoff);
  u16x8 bq1 = *(const u16x8*)(QK + qoff + 32);
#pragma unroll
  for (int j = 0; j < 8; ++j) {  // fold 1/sqrt(Dk)=0.125 (exact exp shift)
    bq0[j] = (u16)(__builtin_bit_cast(u32, bf2f(bq0[j]) * 0.125f) >> 16);
    bq1[j] = (u16)(__builtin_bit_cast(u32, bf2f(bq1[j]) * 0.125f) >> 16);
  }

  float m = -1e9f, lsum = 0.f;
  f32x4 o[4];
#pragma unroll
  for (int dt = 0; dt < 4; ++dt) o[dt] = (f32x4){0.f, 0.f, 0.f, 0.f};

  // preload K chunk 0 (cols 1024.. of QK) and mask word chunk 0
  u16x8 ak0[4], ak1[4];
#pragma unroll
  for (int kt = 0; kt < 4; ++kt) {
    const u16* kp = QK + ((size_t)(b * SEQ + kt * 16 + lo)) * 2048 + 1024 +
                    h * DKH + g * 8;
    ak0[kt] = *(const u16x8*)kp;
    ak1[kt] = *(const u16x8*)(kp + 32);
  }
  int mv = mask[b * SEQ + lane];

#pragma unroll 1
  for (int c = 0; c <= t; ++c) {
    u64 bm = __ballot(mv != 0);

    // S^T tile: mfma(A=K, B=Q) -> D[key][q]; lane: col q=lo,
    // rows key = kt*16 + g*4 + r.
    f32x4 s[4];
#pragma unroll
    for (int kt = 0; kt < 4; ++kt) {
      f32x4 z = (f32x4){0.f, 0.f, 0.f, 0.f};
      s[kt] = MFMA(ak0[kt], bq0, z);
      s[kt] = MFMA(ak1[kt], bq1, s[kt]);
    }

    // prefetch K + mask for next chunk (clamped; regs free after S-MFMAs)
    const int cn = (c < t) ? c + 1 : t;
#pragma unroll
    for (int kt = 0; kt < 4; ++kt) {
      const u16* kp = QK +
                      ((size_t)(b * SEQ + (cn << 6) + kt * 16 + lo)) * 2048 +
                      1024 + h * DKH + g * 8;
      ak0[kt] = *(const u16x8*)kp;
      ak1[kt] = *(const u16x8*)(kp + 32);
    }
    mv = mask[b * SEQ + (cn << 6) + lane];

    if (bm != ~0ull || c == t) {
#pragma unroll
      for (int kt = 0; kt < 4; ++kt)
#pragma unroll
        for (int r = 0; r < 4; ++r) {
          int kl = kt * 16 + g * 4 + r;
          int kk = (c << 6) + kl;
          if ((kk > qrow) || (((bm >> kl) & 1ull) == 0)) s[kt][r] = -1e9f;
        }
    }

    // online softmax: lane owns q-row lo; 16 key-scores local (tree reduce)
    float c0 = fmaxf(fmaxf(s[0][0], s[0][1]), fmaxf(s[0][2], s[0][3]));
    float c1 = fmaxf(fmaxf(s[1][0], s[1][1]), fmaxf(s[1][2], s[1][3]));
    float c2 = fmaxf(fmaxf(s[2][0], s[2][1]), fmaxf(s[2][2], s[2][3]));
    float c3 = fmaxf(fmaxf(s[3][0], s[3][1]), fmaxf(s[3][2], s[3][3]));
    float cm = fmaxf(fmaxf(c0, c1), fmaxf(c2, c3));
    cm = fmaxf(cm, __shfl_xor(cm, 16));
    cm = fmaxf(cm, __shfl_xor(cm, 32));
    float mn = fmaxf(m, cm);
    float fsc = __expf(m - mn);
    m = mn;

    float rsk[4];
#pragma unroll
    for (int kt = 0; kt < 4; ++kt) {
      float p0 = __expf(s[kt][0] - mn);
      float p1 = __expf(s[kt][1] - mn);
      float p2 = __expf(s[kt][2] - mn);
      float p3 = __expf(s[kt][3] - mn);
      rsk[kt] = (p0 + p1) + (p2 + p3);
      // P[q=lo][key=kt*16+g*4..+3] as one ds_write_b64; 16B-chunk XOR
      // swizzle: physchunk = (key>>3) ^ (lo&7)
      u32 w0 = (u32)f2bf(p0) | ((u32)f2bf(p1) << 16);
      u32 w1 = (u32)f2bf(p2) | ((u32)f2bf(p3) << 16);
      int key = kt * 16 + g * 4;
      int byteoff =
          lo * 144 + ((((key >> 3) ^ (lo & 7)) << 4) | ((key & 7) << 1));
      *(u64*)(P + byteoff) = (u64)w0 | ((u64)w1 << 32);
    }

    // issue V for THIS chunk now: covered by reduce/rescale below (~150cy),
    // vv lifetime kept short so allocator stays under ~5 waves/EU budget
    u16x8 vv0[4], vv1[4];
#pragma unroll
    for (int dt = 0; dt < 4; ++dt) {
      const u16* vp = Vt + ((size_t)(h * DKH + dt * 16 + lo)) * (NBATCH * SEQ) +
                      b * SEQ + (c << 6) + g * 8;
      vv0[dt] = *(const u16x8*)vp;
      vv1[dt] = *(const u16x8*)(vp + 32);
    }

    float rs = (rsk[0] + rsk[1]) + (rsk[2] + rsk[3]);
    rs += __shfl_xor(rs, 16);
    rs += __shfl_xor(rs, 32);
    lsum = lsum * fsc + rs;

    // rescale O rows (row index of o regs = g*4+r; fsc lives at lane==row)
#pragma unroll
    for (int r = 0; r < 4; ++r) {
      float fr = __shfl(fsc, (g << 2) + r);
      o[0][r] *= fr;
      o[1][r] *= fr;
      o[2][r] *= fr;
      o[3][r] *= fr;
    }

    // PV: A = P (lane: row q=lo, key=g*8+j / 32+g*8+j), B = V
    u16x8 ap0 = *(const u16x8*)(P + lo * 144 + ((g ^ (lo & 7)) << 4));
    u16x8 ap1 = *(const u16x8*)(P + lo * 144 + (((4 + g) ^ (lo & 7)) << 4));
#pragma unroll
    for (int dt = 0; dt < 4; ++dt) {
      o[dt] = MFMA(ap0, vv0[dt], o[dt]);
      o[dt] = MFMA(ap1, vv1[dt], o[dt]);
    }
  }

  // finalize: divide rows by lsum (held at lane==row), store bf16 ctx
#pragma unroll
  for (int r = 0; r < 4; ++r) {
    float lr = __shfl(lsum, (g << 2) + r);
    float inv = 1.f / lr;
    int row = q0 + wave * 16 + (g << 2) + r;
#pragma unroll
    for (int dt = 0; dt < 4; ++dt) {
      int col = h * DKH + dt * 16 + lo;
      ctx[((size_t)(b * SEQ + row)) * D_MODEL + col] = f2bf(o[dt][r] * inv);
    }
  }
}

// ---------------------------------------------------------------------------
extern "C" void kernel_launch(void* const* d_in, const int* in_sizes, int n_in,
                              void* d_out, int out_size, void* d_ws,
                              size_t ws_size, hipStream_t stream) {
  const float* x = (const float*)d_in[0];
  const int* mask = (const int*)d_in[1];
  const float* Wq = (const float*)d_in[2];
  const float* Wk = (const float*)d_in[3];
  const float* Wv = (const float*)d_in[4];
  const float* Wo = (const float*)d_in[5];
  const float* bo = (const float*)d_in[6];
  float* out = (float*)d_out;

  // workspace layout (bf16 elements); total 46137344 elems = 88 MiB
  u16* xb = (u16*)d_ws;          // 8388608
  u16* wqb = xb + 8388608;       // 1048576 (wkb follows contiguously ->
  u16* wkb = wqb + 1048576;      //  wqb is also the [2048][1024] QK weight)
  u16* wvb = wkb + 1048576;
  u16* wob = wvb + 1048576;
  u16* QKm = wob + 1048576;      // 16777216: [8192][2048], Q cols 0..1023,
                                 //  K cols 1024..2047
  u16* Vt = QKm + 16777216;      // 8388608 (layout: [1024 e][8192 b*S+s])
  u16* ctx = Vt + 8388608;       // 8388608
  if (ws_size < (size_t)46137344 * 2) return;

  conv_all<<<12288, 256, 0, stream>>>(x, Wq, Wk, Wv, Wo, xb, wqb, wkb, wvb, wob);

  // [Q|K] = x [Wq;Wk]^T : (8192x2048), one merged GEMM (weights contiguous)
  gemm_bt<0><<<dim3(16, 64), 256, 0, stream>>>(xb, wqb, QKm, nullptr, nullptr,
                                               8192, 2048, 1024);
  // V^T = Wv x^T : (1024x8192)  -- free transpose via operand swap
  gemm_bt<0><<<dim3(64, 8), 256, 0, stream>>>(wvb, xb, Vt, nullptr, nullptr,
                                              1024, 8192, 1024);

  attn_fwd<<<2048, 256, 0, stream>>>(QKm, Vt, mask, ctx);

  // out = ctx Wo^T + bo : fp32
  gemm_bt<1><<<dim3(8, 64), 256, 0, stream>>>(ctx, wob, nullptr, out, bo, 8192,
                                              1024, 1024);
}

// Round 11
// 316.635 us; speedup vs baseline: 1.5501x; 1.4308x over previous
//
#include <hip/hip_runtime.h>

typedef unsigned short u16;
typedef unsigned int u32;
typedef unsigned long long u64;
typedef __attribute__((ext_vector_type(8))) u16 u16x8;
typedef __attribute__((ext_vector_type(8))) __bf16 bf16x8;
typedef __attribute__((ext_vector_type(4))) float f32x4;

#define D_MODEL 1024
#define SEQ 2048
#define NBATCH 4
#define NHEAD 16
#define DKH 64

__device__ __forceinline__ u16 f2bf(float f) {
  u32 u = __builtin_bit_cast(u32, f);
  u += 0x7fffu + ((u >> 16) & 1u);   // RTNE
  return (u16)(u >> 16);
}
__device__ __forceinline__ float bf2f(u16 h) {
  u32 u = ((u32)h) << 16;
  return __builtin_bit_cast(float, u);
}
__device__ __forceinline__ f32x4 MFMA(u16x8 a, u16x8 b, f32x4 c) {
  return __builtin_amdgcn_mfma_f32_16x16x32_bf16(
      __builtin_bit_cast(bf16x8, a), __builtin_bit_cast(bf16x8, b), c, 0, 0, 0);
}

#define GLD16(gsrc, ldst)                                                     \
  __builtin_amdgcn_global_load_lds(                                           \
      (const __attribute__((address_space(1))) void*)(gsrc),                  \
      (__attribute__((address_space(3))) void*)(ldst), 16, 0, 0)

// ---------------------------------------------------------------------------
// fp32 -> bf16 conversion for x (8388608 elems) + Wq/Wk/Wv/Wo (1048576 each).
// ---------------------------------------------------------------------------
__global__ __launch_bounds__(256) void conv_all(
    const float* __restrict__ x, const float* __restrict__ wq,
    const float* __restrict__ wk, const float* __restrict__ wv,
    const float* __restrict__ wo, u16* __restrict__ xb, u16* __restrict__ wqb,
    u16* __restrict__ wkb, u16* __restrict__ wvb, u16* __restrict__ wob) {
  long qd = (long)blockIdx.x * 256 + threadIdx.x;
  long e = qd << 2;
  const float* src;
  u16* dst;
  long off;
  if (e < 8388608L) {
    src = x; dst = xb; off = e;
  } else {
    long j = e - 8388608L;
    int w = (int)(j >> 20);
    off = j & 1048575L;
    src = (w == 0) ? wq : (w == 1) ? wk : (w == 2) ? wv : wo;
    dst = (w == 0) ? wqb : (w == 1) ? wkb : (w == 2) ? wvb : wob;
  }
  float4 v = *(const float4*)(src + off);
  u32 lo32 = (u32)f2bf(v.x) | ((u32)f2bf(v.y) << 16);
  u32 hi32 = (u32)f2bf(v.z) | ((u32)f2bf(v.w) << 16);
  *(u64*)(dst + off) = (u64)lo32 | ((u64)hi32 << 32);
}

// ---------------------------------------------------------------------------
// C[M][N] = A[M][K] * Bm[N][K]^T   (m97 structure).
// MODE 0: bf16 row-major -> out0.
// MODE 1: fp32 + bias -> Cf.
// MODE 2 (QK proj): col<1024 -> Qm row-major [8192][1024] (out0);
//   col>=1024 -> K chunk-packed+swizzled Kc (out1):
//   unit(key,d16) at key*8 + (d16 ^ (key&7)) within 4096-elem chunk.
// MODE 3 (V^T proj): row=dk_global, col=b*2048+s -> Vc chunk-packed:
//   unit(dk,k16) at dk*8 + (k16 ^ (dk&7)).
// ---------------------------------------------------------------------------
template <int MODE>
__global__ __launch_bounds__(256) void gemm_bt(
    const u16* __restrict__ A, const u16* __restrict__ Bm,
    u16* __restrict__ out0, u16* __restrict__ out1, float* __restrict__ Cf,
    const float* __restrict__ bias, int M, int N, int K) {
  __shared__ u16 As[128 * 64];
  __shared__ u16 Bs[128 * 64];
  const int tid = threadIdx.x;
  const int lane = tid & 63, wave = tid >> 6;
  const int lo = lane & 15, g = lane >> 4;
  const int mBase = blockIdx.y * 128, nBase = blockIdx.x * 128;
  const int wr = wave >> 1, wc = wave & 1;

  f32x4 acc[4][4];
#pragma unroll
  for (int mi = 0; mi < 4; ++mi)
#pragma unroll
    for (int ni = 0; ni < 4; ++ni) acc[mi][ni] = (f32x4){0.f, 0.f, 0.f, 0.f};

  const int nK = K >> 6;
  for (int kb = 0; kb < nK; ++kb) {
    __syncthreads();
    const u16* Ab = A + (size_t)mBase * K + kb * 64;
    const u16* Bb = Bm + (size_t)nBase * K + kb * 64;
#pragma unroll
    for (int i = 0; i < 4; ++i) {
      int flat = (i * 256 + tid) * 8;
      int r = flat >> 6, c = flat & 63;
      GLD16(Ab + (size_t)r * K + c, As + (i * 256 + wave * 64) * 8);
    }
#pragma unroll
    for (int i = 0; i < 4; ++i) {
      int flat = (i * 256 + tid) * 8;
      int r = flat >> 6, c = flat & 63;
      GLD16(Bb + (size_t)r * K + c, Bs + (i * 256 + wave * 64) * 8);
    }
    __syncthreads();

#pragma unroll
    for (int kk = 0; kk < 64; kk += 32) {
      u16x8 a[4], b[4];
#pragma unroll
      for (int mi = 0; mi < 4; ++mi)
        a[mi] = *(const u16x8*)&As[(wr * 64 + mi * 16 + lo) * 64 + kk + g * 8];
#pragma unroll
      for (int ni = 0; ni < 4; ++ni)
        b[ni] = *(const u16x8*)&Bs[(wc * 64 + ni * 16 + lo) * 64 + kk + g * 8];
#pragma unroll
      for (int mi = 0; mi < 4; ++mi)
#pragma unroll
        for (int ni = 0; ni < 4; ++ni)
          acc[mi][ni] = MFMA(a[mi], b[ni], acc[mi][ni]);
    }
  }

#pragma unroll
  for (int mi = 0; mi < 4; ++mi)
#pragma unroll
    for (int ni = 0; ni < 4; ++ni) {
      int row0 = mBase + wr * 64 + mi * 16 + g * 4;
      int col = nBase + wc * 64 + ni * 16 + lo;
      float bv = 0.f;
      if constexpr (MODE == 1) bv = bias[col];
#pragma unroll
      for (int r = 0; r < 4; ++r) {
        int row = row0 + r;
        float v = acc[mi][ni][r];
        if constexpr (MODE == 0) {
          out0[(size_t)row * N + col] = f2bf(v);
        } else if constexpr (MODE == 1) {
          Cf[(size_t)row * N + col] = v + bv;
        } else if constexpr (MODE == 2) {
          if (col < 1024) {
            out0[(size_t)row * 1024 + col] = f2bf(v);
          } else {
            int b = row >> 11, s = row & 2047, c = s >> 6, key = s & 63;
            int col2 = col - 1024;
            int h = col2 >> 6, dk = col2 & 63;
            int d16 = dk >> 3, dlo = dk & 7;
            out1[((size_t)((b * 16 + h) * 32 + c)) * 4096 +
                 (key * 8 + (d16 ^ (key & 7))) * 8 + dlo] = f2bf(v);
          }
        } else {  // MODE 3
          int h = row >> 6, dk = row & 63;
          int b = col >> 11, s = col & 2047, c = s >> 6, key = s & 63;
          int k16 = key >> 3, klo = key & 7;
          out0[((size_t)((b * 16 + h) * 32 + c)) * 4096 +
               (dk * 8 + (k16 ^ (dk & 7))) * 8 + klo] = f2bf(v);
        }
      }
    }
}

// ---------------------------------------------------------------------------
// Flash attention v5: chunk-packed contiguous K/V + shared LDS staging.
// Prior rounds: K read 64x128B at 4KB stride, V at 16KB stride (power-of-2
// channel aliasing) and each of 4 waves loaded the same chunk redundantly ->
// per-iteration latency ~10k cy (MfmaUtil 5%, VALUBusy 23%, all idle).
// Now: Kc/Vc chunks are 8KB CONTIGUOUS (pre-swizzled 16B units); one
// global_load_lds staging (coalesced base+tid*16), double-buffered, shared
// by all 4 waves; one barrier per iteration; ds_reads <=2-way conflicts.
// ---------------------------------------------------------------------------
__global__ __launch_bounds__(256) void attn_fwd(
    const u16* __restrict__ Qm, const u16* __restrict__ Kc,
    const u16* __restrict__ Vc, const int* __restrict__ mask,
    u16* __restrict__ ctx) {
  __shared__ u16 Kl[2][4096];
  __shared__ u16 Vl[2][4096];
  __shared__ u16 Plds[4][16 * 72];  // per-wave 16 rows x 144B stride
  // bid0 -> (xcd, group, tile): LPT (longest tiles first), XCD-grouped (b,h).
  const int bid0 = blockIdx.x;
  const int xcd = bid0 & 7, gi = (bid0 >> 3) & 7, tz = bid0 >> 6;
  const int t = 31 - tz;                 // this block's q-tile, t+1 chunks
  const int gh = xcd * 8 + gi;           // (b,h) group 0..63
  const int h = gh & 15, b = gh >> 4;
  const int q0 = t << 6;
  const int tid = threadIdx.x;
  const int lane = tid & 63, wave = tid >> 6;
  const int lo = lane & 15, g = lane >> 4;
  char* P = (char*)&Plds[wave][0];

  const int qrow = q0 + wave * 16 + lo;  // this lane's q row (softmax owner)

  // Q fragment (B-operand): lane holds Q[q=lo][dk=g*8+j], x2 for dk 0..63.
  const size_t qoff = ((size_t)(b * SEQ + qrow)) * 1024 + h * DKH + g * 8;
  u16x8 bq0 = *(const u16x8*)(Qm + qoff);
  u16x8 bq1 = *(const u16x8*)(Qm + qoff + 32);
#pragma unroll
  for (int j = 0; j < 8; ++j) {  // fold 1/sqrt(Dk)=0.125 (exact exp shift)
    bq0[j] = (u16)(__builtin_bit_cast(u32, bf2f(bq0[j]) * 0.125f) >> 16);
    bq1[j] = (u16)(__builtin_bit_cast(u32, bf2f(bq1[j]) * 0.125f) >> 16);
  }

  const u16* KcB = Kc + (size_t)gh * 131072;  // 32 chunks x 4096 elems
  const u16* VcB = Vc + (size_t)gh * 131072;

#define STAGE(bufi, cc)                                                       \
  {                                                                           \
    const u16* kp_ = KcB + (size_t)(cc)*4096;                                 \
    const u16* vp_ = VcB + (size_t)(cc)*4096;                                 \
    GLD16(kp_ + tid * 8, &Kl[bufi][wave * 512]);                              \
    GLD16(kp_ + 2048 + tid * 8, &Kl[bufi][2048 + wave * 512]);                \
    GLD16(vp_ + tid * 8, &Vl[bufi][wave * 512]);                              \
    GLD16(vp_ + 2048 + tid * 8, &Vl[bufi][2048 + wave * 512]);                \
  }

  float m = -1e9f, lsum = 0.f;
  f32x4 o[4];
#pragma unroll
  for (int dt = 0; dt < 4; ++dt) o[dt] = (f32x4){0.f, 0.f, 0.f, 0.f};

  int cur = 0;
  STAGE(0, 0);
  int mv = mask[b * SEQ + lane];

#pragma unroll 1
  for (int c = 0; c <= t; ++c) {
    __syncthreads();  // staged buf[cur] visible (drains vmcnt)
    if (c < t) STAGE(cur ^ 1, c + 1);

    u64 bm = __ballot(mv != 0);

    // K fragments from LDS (pre-swizzled units: d16 ^ (key&7))
    u16x8 ak0[4], ak1[4];
#pragma unroll
    for (int kt = 0; kt < 4; ++kt) {
      int key = kt * 16 + lo, sw = key & 7;
      ak0[kt] = *(const u16x8*)&Kl[cur][(key * 8 + (g ^ sw)) * 8];
      ak1[kt] = *(const u16x8*)&Kl[cur][(key * 8 + ((4 + g) ^ sw)) * 8];
    }

    // S^T tile: mfma(A=K, B=Q) -> D[key][q]; lane: col q=lo,
    // rows key = kt*16 + g*4 + r.
    f32x4 s[4];
#pragma unroll
    for (int kt = 0; kt < 4; ++kt) {
      f32x4 z = (f32x4){0.f, 0.f, 0.f, 0.f};
      s[kt] = MFMA(ak0[kt], bq0, z);
      s[kt] = MFMA(ak1[kt], bq1, s[kt]);
    }

    const int cn = (c < t) ? c + 1 : t;
    mv = mask[b * SEQ + (cn << 6) + lane];  // prefetch next mask word

    if (bm != ~0ull || c == t) {
#pragma unroll
      for (int kt = 0; kt < 4; ++kt)
#pragma unroll
        for (int r = 0; r < 4; ++r) {
          int kl = kt * 16 + g * 4 + r;
          int kk = (c << 6) + kl;
          if ((kk > qrow) || (((bm >> kl) & 1ull) == 0)) s[kt][r] = -1e9f;
        }
    }

    // online softmax: lane owns q-row lo; 16 key-scores local (tree reduce)
    float c0 = fmaxf(fmaxf(s[0][0], s[0][1]), fmaxf(s[0][2], s[0][3]));
    float c1 = fmaxf(fmaxf(s[1][0], s[1][1]), fmaxf(s[1][2], s[1][3]));
    float c2 = fmaxf(fmaxf(s[2][0], s[2][1]), fmaxf(s[2][2], s[2][3]));
    float c3 = fmaxf(fmaxf(s[3][0], s[3][1]), fmaxf(s[3][2], s[3][3]));
    float cm = fmaxf(fmaxf(c0, c1), fmaxf(c2, c3));
    cm = fmaxf(cm, __shfl_xor(cm, 16));
    cm = fmaxf(cm, __shfl_xor(cm, 32));
    float mn = fmaxf(m, cm);
    float fsc = __expf(m - mn);
    m = mn;

    float rsk[4];
#pragma unroll
    for (int kt = 0; kt < 4; ++kt) {
      float p0 = __expf(s[kt][0] - mn);
      float p1 = __expf(s[kt][1] - mn);
      float p2 = __expf(s[kt][2] - mn);
      float p3 = __expf(s[kt][3] - mn);
      rsk[kt] = (p0 + p1) + (p2 + p3);
      // P[q=lo][key=kt*16+g*4..+3] as one ds_write_b64; 16B-chunk XOR
      // swizzle: physchunk = (key>>3) ^ (lo&7)
      u32 w0 = (u32)f2bf(p0) | ((u32)f2bf(p1) << 16);
      u32 w1 = (u32)f2bf(p2) | ((u32)f2bf(p3) << 16);
      int key = kt * 16 + g * 4;
      int byteoff =
          lo * 144 + ((((key >> 3) ^ (lo & 7)) << 4) | ((key & 7) << 1));
      *(u64*)(P + byteoff) = (u64)w0 | ((u64)w1 << 32);
    }

    float rs = (rsk[0] + rsk[1]) + (rsk[2] + rsk[3]);
    rs += __shfl_xor(rs, 16);
    rs += __shfl_xor(rs, 32);
    lsum = lsum * fsc + rs;

    // rescale O rows (row index of o regs = g*4+r; fsc lives at lane==row)
#pragma unroll
    for (int r = 0; r < 4; ++r) {
      float fr = __shfl(fsc, (g << 2) + r);
      o[0][r] *= fr;
      o[1][r] *= fr;
      o[2][r] *= fr;
      o[3][r] *= fr;
    }

    // PV: A = P (lane: row q=lo, key=g*8+j / 32+g*8+j), B = V from LDS
    u16x8 ap0 = *(const u16x8*)(P + lo * 144 + ((g ^ (lo & 7)) << 4));
    u16x8 ap1 = *(const u16x8*)(P + lo * 144 + (((4 + g) ^ (lo & 7)) << 4));
#pragma unroll
    for (int dt = 0; dt < 4; ++dt) {
      int dk = dt * 16 + lo, sw = dk & 7;
      u16x8 bv0 = *(const u16x8*)&Vl[cur][(dk * 8 + (g ^ sw)) * 8];
      u16x8 bv1 = *(const u16x8*)&Vl[cur][(dk * 8 + ((4 + g) ^ sw)) * 8];
      o[dt] = MFMA(ap0, bv0, o[dt]);
      o[dt] = MFMA(ap1, bv1, o[dt]);
    }

    cur ^= 1;
  }

  // finalize: divide rows by lsum (held at lane==row), store bf16 ctx
#pragma unroll
  for (int r = 0; r < 4; ++r) {
    float lr = __shfl(lsum, (g << 2) + r);
    float inv = 1.f / lr;
    int row = q0 + wave * 16 + (g << 2) + r;
#pragma unroll
    for (int dt = 0; dt < 4; ++dt) {
      int col = h * DKH + dt * 16 + lo;
      ctx[((size_t)(b * SEQ + row)) * D_MODEL + col] = f2bf(o[dt][r] * inv);
    }
  }
}

// ---------------------------------------------------------------------------
extern "C" void kernel_launch(void* const* d_in, const int* in_sizes, int n_in,
                              void* d_out, int out_size, void* d_ws,
                              size_t ws_size, hipStream_t stream) {
  const float* x = (const float*)d_in[0];
  const int* mask = (const int*)d_in[1];
  const float* Wq = (const float*)d_in[2];
  const float* Wk = (const float*)d_in[3];
  const float* Wv = (const float*)d_in[4];
  const float* Wo = (const float*)d_in[5];
  const float* bo = (const float*)d_in[6];
  float* out = (float*)d_out;

  // workspace layout (bf16 elements); total 46137344 elems = 88 MiB
  u16* xb = (u16*)d_ws;          // 8388608
  u16* wqb = xb + 8388608;       // 1048576 (wkb follows contiguously ->
  u16* wkb = wqb + 1048576;      //  wqb is also the [2048][1024] QK weight)
  u16* wvb = wkb + 1048576;
  u16* wob = wvb + 1048576;
  u16* Qm = wob + 1048576;       // 8388608: [8192][1024] row-major
  u16* Kc = Qm + 8388608;        // 8388608: chunk-packed swizzled K
  u16* Vc = Kc + 8388608;        // 8388608: chunk-packed swizzled V^T
  u16* ctx = Vc + 8388608;       // 8388608
  if (ws_size < (size_t)46137344 * 2) return;

  conv_all<<<12288, 256, 0, stream>>>(x, Wq, Wk, Wv, Wo, xb, wqb, wkb, wvb, wob);

  // [Q|K] = x [Wq;Wk]^T : (8192x2048); Q -> Qm row-major, K -> Kc packed
  gemm_bt<2><<<dim3(16, 64), 256, 0, stream>>>(xb, wqb, Qm, Kc, nullptr,
                                               nullptr, 8192, 2048, 1024);
  // V^T = Wv x^T : (1024x8192) -> Vc chunk-packed
  gemm_bt<3><<<dim3(64, 8), 256, 0, stream>>>(wvb, xb, Vc, nullptr, nullptr,
                                              nullptr, 1024, 8192, 1024);

  attn_fwd<<<2048, 256, 0, stream>>>(Qm, Kc, Vc, mask, ctx);

  // out = ctx Wo^T + bo : fp32
  gemm_bt<1><<<dim3(8, 64), 256, 0, stream>>>(ctx, wob, nullptr, nullptr, out,
                                              bo, 8192, 1024, 1024);
}

// Round 14
// 299.406 us; speedup vs baseline: 1.6393x; 1.0575x over previous
//
#include <hip/hip_runtime.h>
#include <math.h>

typedef unsigned short u16;
typedef unsigned int u32;
typedef unsigned long long u64;
typedef __attribute__((ext_vector_type(8))) u16 u16x8;
typedef __attribute__((ext_vector_type(8))) __bf16 bf16x8;
typedef __attribute__((ext_vector_type(4))) float f32x4;

#define D_MODEL 1024
#define SEQ 2048
#define NBATCH 4
#define NHEAD 16
#define DKH 64

__device__ __forceinline__ u16 f2bf(float f) {
  u32 u = __builtin_bit_cast(u32, f);
  u += 0x7fffu + ((u >> 16) & 1u);   // RTNE
  return (u16)(u >> 16);
}
__device__ __forceinline__ float bf2f(u16 h) {
  u32 u = ((u32)h) << 16;
  return __builtin_bit_cast(float, u);
}
// 2^x: lowers to a single v_exp_f32 (HW op is base-2). NOTE: __exp2f does
// NOT exist on this toolchain (glibc macro collision) -- use exp2f.
__device__ __forceinline__ float E2(float x) { return exp2f(x); }

__device__ __forceinline__ f32x4 MFMA(u16x8 a, u16x8 b, f32x4 c) {
  return __builtin_amdgcn_mfma_f32_16x16x32_bf16(
      __builtin_bit_cast(bf16x8, a), __builtin_bit_cast(bf16x8, b), c, 0, 0, 0);
}

#define GLD16(gsrc, ldst)                                                     \
  __builtin_amdgcn_global_load_lds(                                           \
      (const __attribute__((address_space(1))) void*)(gsrc),                  \
      (__attribute__((address_space(3))) void*)(ldst), 16, 0, 0)

// ---------------------------------------------------------------------------
// fp32 -> bf16 conversion for x (8388608 elems) + Wq/Wk/Wv/Wo (1048576 each).
// ---------------------------------------------------------------------------
__global__ __launch_bounds__(256) void conv_all(
    const float* __restrict__ x, const float* __restrict__ wq,
    const float* __restrict__ wk, const float* __restrict__ wv,
    const float* __restrict__ wo, u16* __restrict__ xb, u16* __restrict__ wqb,
    u16* __restrict__ wkb, u16* __restrict__ wvb, u16* __restrict__ wob) {
  long qd = (long)blockIdx.x * 256 + threadIdx.x;
  long e = qd << 2;
  const float* src;
  u16* dst;
  long off;
  if (e < 8388608L) {
    src = x; dst = xb; off = e;
  } else {
    long j = e - 8388608L;
    int w = (int)(j >> 20);
    off = j & 1048575L;
    src = (w == 0) ? wq : (w == 1) ? wk : (w == 2) ? wv : wo;
    dst = (w == 0) ? wqb : (w == 1) ? wkb : (w == 2) ? wvb : wob;
  }
  float4 v = *(const float4*)(src + off);
  u32 lo32 = (u32)f2bf(v.x) | ((u32)f2bf(v.y) << 16);
  u32 hi32 = (u32)f2bf(v.z) | ((u32)f2bf(v.w) << 16);
  *(u64*)(dst + off) = (u64)lo32 | ((u64)hi32 << 32);
}

// ---------------------------------------------------------------------------
// C[M][N] = A[M][K] * Bm[N][K]^T   (m97 structure).
// MODE 0: bf16 row-major -> out0.
// MODE 1: fp32 + bias -> Cf.
// MODE 4 (fused QKV, N=3072): col<1024 -> Qm row-major [8192][1024] (out0);
//   col in [1024,2048) -> Kc chunk-packed+swizzled (out1):
//     value K[b,s][h,dk] -> base[(b*16+h)*32+c] + (key*8 + (d16^(key&7)))*8+dlo
//   col >= 2048 -> Vc chunk-packed+swizzled (out2):
//     value V[b,s][h,dk] -> base[(b*16+h)*32+c] + (dk*8 + (k16^(dk&7)))*8+klo
// ---------------------------------------------------------------------------
template <int MODE>
__global__ __launch_bounds__(256) void gemm_bt(
    const u16* __restrict__ A, const u16* __restrict__ Bm,
    u16* __restrict__ out0, u16* __restrict__ out1, u16* __restrict__ out2,
    float* __restrict__ Cf, const float* __restrict__ bias, int M, int N,
    int K) {
  __shared__ u16 As[128 * 64];
  __shared__ u16 Bs[128 * 64];
  const int tid = threadIdx.x;
  const int lane = tid & 63, wave = tid >> 6;
  const int lo = lane & 15, g = lane >> 4;
  const int mBase = blockIdx.y * 128, nBase = blockIdx.x * 128;
  const int wr = wave >> 1, wc = wave & 1;

  f32x4 acc[4][4];
#pragma unroll
  for (int mi = 0; mi < 4; ++mi)
#pragma unroll
    for (int ni = 0; ni < 4; ++ni) acc[mi][ni] = (f32x4){0.f, 0.f, 0.f, 0.f};

  const int nK = K >> 6;
  for (int kb = 0; kb < nK; ++kb) {
    __syncthreads();
    const u16* Ab = A + (size_t)mBase * K + kb * 64;
    const u16* Bb = Bm + (size_t)nBase * K + kb * 64;
#pragma unroll
    for (int i = 0; i < 4; ++i) {
      int flat = (i * 256 + tid) * 8;
      int r = flat >> 6, c = flat & 63;
      GLD16(Ab + (size_t)r * K + c, As + (i * 256 + wave * 64) * 8);
    }
#pragma unroll
    for (int i = 0; i < 4; ++i) {
      int flat = (i * 256 + tid) * 8;
      int r = flat >> 6, c = flat & 63;
      GLD16(Bb + (size_t)r * K + c, Bs + (i * 256 + wave * 64) * 8);
    }
    __syncthreads();

#pragma unroll
    for (int kk = 0; kk < 64; kk += 32) {
      u16x8 a[4], b[4];
#pragma unroll
      for (int mi = 0; mi < 4; ++mi)
        a[mi] = *(const u16x8*)&As[(wr * 64 + mi * 16 + lo) * 64 + kk + g * 8];
#pragma unroll
      for (int ni = 0; ni < 4; ++ni)
        b[ni] = *(const u16x8*)&Bs[(wc * 64 + ni * 16 + lo) * 64 + kk + g * 8];
#pragma unroll
      for (int mi = 0; mi < 4; ++mi)
#pragma unroll
        for (int ni = 0; ni < 4; ++ni)
          acc[mi][ni] = MFMA(a[mi], b[ni], acc[mi][ni]);
    }
  }

#pragma unroll
  for (int mi = 0; mi < 4; ++mi)
#pragma unroll
    for (int ni = 0; ni < 4; ++ni) {
      int row0 = mBase + wr * 64 + mi * 16 + g * 4;
      int col = nBase + wc * 64 + ni * 16 + lo;
      float bv = 0.f;
      if constexpr (MODE == 1) bv = bias[col];
#pragma unroll
      for (int r = 0; r < 4; ++r) {
        int row = row0 + r;
        float v = acc[mi][ni][r];
        if constexpr (MODE == 0) {
          out0[(size_t)row * N + col] = f2bf(v);
        } else if constexpr (MODE == 1) {
          Cf[(size_t)row * N + col] = v + bv;
        } else {  // MODE 4
          if (col < 1024) {
            out0[(size_t)row * 1024 + col] = f2bf(v);
          } else if (col < 2048) {
            int bb = row >> 11, s = row & 2047, cc = s >> 6, key = s & 63;
            int col2 = col - 1024;
            int hh = col2 >> 6, dk = col2 & 63;
            int d16 = dk >> 3, dlo = dk & 7;
            out1[((size_t)((bb * 16 + hh) * 32 + cc)) * 4096 +
                 (key * 8 + (d16 ^ (key & 7))) * 8 + dlo] = f2bf(v);
          } else {
            int bb = row >> 11, s = row & 2047, cc = s >> 6, key = s & 63;
            int col2 = col - 2048;
            int hh = col2 >> 6, dk = col2 & 63;
            int k16 = key >> 3, klo = key & 7;
            out2[((size_t)((bb * 16 + hh) * 32 + cc)) * 4096 +
                 (dk * 8 + (k16 ^ (dk & 7))) * 8 + klo] = f2bf(v);
          }
        }
      }
    }
}

// ---------------------------------------------------------------------------
// Flash attention v6: v5 (chunk-packed K/V, shared dbuf LDS staging) +
//  - Plds stride 144->128B: total LDS 40960B -> 4 blocks/CU (was 3)
//  - exp2-domain softmax (0.125*log2e folded into Q; exp2f, no pre-mul)
//  - T13 defer-rescale: skip o-rescale/m-update when __all(cm <= m+8)
// ---------------------------------------------------------------------------
__global__ __launch_bounds__(256) void attn_fwd(
    const u16* __restrict__ Qm, const u16* __restrict__ Kc,
    const u16* __restrict__ Vc, const int* __restrict__ mask,
    u16* __restrict__ ctx) {
  __shared__ u16 Kl[2][4096];
  __shared__ u16 Vl[2][4096];
  __shared__ u16 Plds[4][16 * 64];  // per-wave 16 rows x 128B stride
  // bid0 -> (xcd, group, tile): LPT (longest tiles first), XCD-grouped (b,h).
  const int bid0 = blockIdx.x;
  const int xcd = bid0 & 7, gi = (bid0 >> 3) & 7, tz = bid0 >> 6;
  const int t = 31 - tz;                 // this block's q-tile, t+1 chunks
  const int gh = xcd * 8 + gi;           // (b,h) group 0..63
  const int h = gh & 15, b = gh >> 4;
  const int q0 = t << 6;
  const int tid = threadIdx.x;
  const int lane = tid & 63, wave = tid >> 6;
  const int lo = lane & 15, g = lane >> 4;
  char* P = (char*)&Plds[wave][0];

  const int qrow = q0 + wave * 16 + lo;  // this lane's q row (softmax owner)

  // Q fragment (B-operand): lane holds Q[q=lo][dk=g*8+j], x2 for dk 0..63.
  // scale = 1/sqrt(Dk) * log2(e): softmax runs in exp2 domain.
  const float SCL = 0.125f * 1.44269504f;
  const size_t qoff = ((size_t)(b * SEQ + qrow)) * 1024 + h * DKH + g * 8;
  u16x8 bq0 = *(const u16x8*)(Qm + qoff);
  u16x8 bq1 = *(const u16x8*)(Qm + qoff + 32);
#pragma unroll
  for (int j = 0; j < 8; ++j) {
    bq0[j] = f2bf(bf2f(bq0[j]) * SCL);
    bq1[j] = f2bf(bf2f(bq1[j]) * SCL);
  }

  const u16* KcB = Kc + (size_t)gh * 131072;  // 32 chunks x 4096 elems
  const u16* VcB = Vc + (size_t)gh * 131072;

#define STAGE(bufi, cc)                                                       \
  {                                                                           \
    const u16* kp_ = KcB + (size_t)(cc)*4096;                                 \
    const u16* vp_ = VcB + (size_t)(cc)*4096;                                 \
    GLD16(kp_ + tid * 8, &Kl[bufi][wave * 512]);                              \
    GLD16(kp_ + 2048 + tid * 8, &Kl[bufi][2048 + wave * 512]);                \
    GLD16(vp_ + tid * 8, &Vl[bufi][wave * 512]);                              \
    GLD16(vp_ + 2048 + tid * 8, &Vl[bufi][2048 + wave * 512]);                \
  }

  float m = -1e9f, lsum = 0.f;
  f32x4 o[4];
#pragma unroll
  for (int dt = 0; dt < 4; ++dt) o[dt] = (f32x4){0.f, 0.f, 0.f, 0.f};

  int cur = 0;
  STAGE(0, 0);
  int mv = mask[b * SEQ + lane];

#pragma unroll 1
  for (int c = 0; c <= t; ++c) {
    __syncthreads();  // staged buf[cur] visible (drains vmcnt)
    if (c < t) STAGE(cur ^ 1, c + 1);

    u64 bm = __ballot(mv != 0);

    // K fragments from LDS (pre-swizzled units: d16 ^ (key&7))
    u16x8 ak0[4], ak1[4];
#pragma unroll
    for (int kt = 0; kt < 4; ++kt) {
      int key = kt * 16 + lo, sw = key & 7;
      ak0[kt] = *(const u16x8*)&Kl[cur][(key * 8 + (g ^ sw)) * 8];
      ak1[kt] = *(const u16x8*)&Kl[cur][(key * 8 + ((4 + g) ^ sw)) * 8];
    }

    // S^T tile: mfma(A=K, B=Q) -> D[key][q]; lane: col q=lo,
    // rows key = kt*16 + g*4 + r.  (values are log2-domain scores)
    f32x4 s[4];
#pragma unroll
    for (int kt = 0; kt < 4; ++kt) {
      f32x4 z = (f32x4){0.f, 0.f, 0.f, 0.f};
      s[kt] = MFMA(ak0[kt], bq0, z);
      s[kt] = MFMA(ak1[kt], bq1, s[kt]);
    }

    const int cn = (c < t) ? c + 1 : t;
    mv = mask[b * SEQ + (cn << 6) + lane];  // prefetch next mask word

    if (bm != ~0ull || c == t) {
#pragma unroll
      for (int kt = 0; kt < 4; ++kt)
#pragma unroll
        for (int r = 0; r < 4; ++r) {
          int kl = kt * 16 + g * 4 + r;
          int kk = (c << 6) + kl;
          if ((kk > qrow) || (((bm >> kl) & 1ull) == 0)) s[kt][r] = -1e9f;
        }
    }

    // online softmax (exp2 domain): lane owns q-row lo; 16 scores local
    float c0 = fmaxf(fmaxf(s[0][0], s[0][1]), fmaxf(s[0][2], s[0][3]));
    float c1 = fmaxf(fmaxf(s[1][0], s[1][1]), fmaxf(s[1][2], s[1][3]));
    float c2 = fmaxf(fmaxf(s[2][0], s[2][1]), fmaxf(s[2][2], s[2][3]));
    float c3 = fmaxf(fmaxf(s[3][0], s[3][1]), fmaxf(s[3][2], s[3][3]));
    float cm = fmaxf(fmaxf(c0, c1), fmaxf(c2, c3));
    cm = fmaxf(cm, __shfl_xor(cm, 16));
    cm = fmaxf(cm, __shfl_xor(cm, 32));
    // T13 defer: if no row grew its max by >8, keep old m (P <= 2^8)
    const bool defer = (__all(cm <= m + 8.0f) != 0);
    const float mn = defer ? m : fmaxf(m, cm);

    float rsk[4];
#pragma unroll
    for (int kt = 0; kt < 4; ++kt) {
      float p0 = E2(s[kt][0] - mn);
      float p1 = E2(s[kt][1] - mn);
      float p2 = E2(s[kt][2] - mn);
      float p3 = E2(s[kt][3] - mn);
      rsk[kt] = (p0 + p1) + (p2 + p3);
      // P[q=lo][key=kt*16+g*4..+3] as one ds_write_b64; 16B-unit XOR
      // swizzle: physunit = (key>>3) ^ (lo&7); 128B row stride
      u32 w0 = (u32)f2bf(p0) | ((u32)f2bf(p1) << 16);
      u32 w1 = (u32)f2bf(p2) | ((u32)f2bf(p3) << 16);
      int key = kt * 16 + g * 4;
      int byteoff =
          lo * 128 + ((((key >> 3) ^ (lo & 7)) << 4) | ((key & 7) << 1));
      *(u64*)(P + byteoff) = (u64)w0 | ((u64)w1 << 32);
    }

    float rs = (rsk[0] + rsk[1]) + (rsk[2] + rsk[3]);
    rs += __shfl_xor(rs, 16);
    rs += __shfl_xor(rs, 32);
    if (defer) {
      lsum += rs;
    } else {
      float fsc = E2(m - mn);
      lsum = lsum * fsc + rs;
      m = mn;
      // rescale O rows (row of o regs = g*4+r; fsc lives at lane==row)
#pragma unroll
      for (int r = 0; r < 4; ++r) {
        float fr = __shfl(fsc, (g << 2) + r);
        o[0][r] *= fr;
        o[1][r] *= fr;
        o[2][r] *= fr;
        o[3][r] *= fr;
      }
    }

    // PV: A = P (lane: row q=lo, key=g*8+j / 32+g*8+j), B = V from LDS
    u16x8 ap0 = *(const u16x8*)(P + lo * 128 + ((g ^ (lo & 7)) << 4));
    u16x8 ap1 = *(const u16x8*)(P + lo * 128 + (((4 + g) ^ (lo & 7)) << 4));
#pragma unroll
    for (int dt = 0; dt < 4; ++dt) {
      int dk = dt * 16 + lo, sw = dk & 7;
      u16x8 bv0 = *(const u16x8*)&Vl[cur][(dk * 8 + (g ^ sw)) * 8];
      u16x8 bv1 = *(const u16x8*)&Vl[cur][(dk * 8 + ((4 + g) ^ sw)) * 8];
      o[dt] = MFMA(ap0, bv0, o[dt]);
      o[dt] = MFMA(ap1, bv1, o[dt]);
    }

    cur ^= 1;
  }

  // finalize: divide rows by lsum (held at lane==row), store bf16 ctx
#pragma unroll
  for (int r = 0; r < 4; ++r) {
    float lr = __shfl(lsum, (g << 2) + r);
    float inv = 1.f / lr;
    int row = q0 + wave * 16 + (g << 2) + r;
#pragma unroll
    for (int dt = 0; dt < 4; ++dt) {
      int col = h * DKH + dt * 16 + lo;
      ctx[((size_t)(b * SEQ + row)) * D_MODEL + col] = f2bf(o[dt][r] * inv);
    }
  }
}

// ---------------------------------------------------------------------------
extern "C" void kernel_launch(void* const* d_in, const int* in_sizes, int n_in,
                              void* d_out, int out_size, void* d_ws,
                              size_t ws_size, hipStream_t stream) {
  const float* x = (const float*)d_in[0];
  const int* mask = (const int*)d_in[1];
  const float* Wq = (const float*)d_in[2];
  const float* Wk = (const float*)d_in[3];
  const float* Wv = (const float*)d_in[4];
  const float* Wo = (const float*)d_in[5];
  const float* bo = (const float*)d_in[6];
  float* out = (float*)d_out;

  // workspace layout (bf16 elements); total 46137344 elems = 88 MiB
  u16* xb = (u16*)d_ws;          // 8388608
  u16* wqb = xb + 8388608;       // 1048576 (wqb/wkb/wvb contiguous ->
  u16* wkb = wqb + 1048576;      //  wqb is the [3072][1024] QKV weight)
  u16* wvb = wkb + 1048576;
  u16* wob = wvb + 1048576;
  u16* Qm = wob + 1048576;       // 8388608: [8192][1024] row-major
  u16* Kc = Qm + 8388608;        // 8388608: chunk-packed swizzled K
  u16* Vc = Kc + 8388608;        // 8388608: chunk-packed swizzled V^T
  u16* ctx = Vc + 8388608;       // 8388608
  if (ws_size < (size_t)46137344 * 2) return;

  conv_all<<<12288, 256, 0, stream>>>(x, Wq, Wk, Wv, Wo, xb, wqb, wkb, wvb, wob);

  // fused [Q|K|V] = x [Wq;Wk;Wv]^T : (8192x3072), one GEMM;
  // epilogue routes Q -> Qm row-major, K -> Kc packed, V -> Vc packed
  gemm_bt<4><<<dim3(24, 64), 256, 0, stream>>>(xb, wqb, Qm, Kc, Vc, nullptr,
                                               nullptr, 8192, 3072, 1024);

  attn_fwd<<<2048, 256, 0, stream>>>(Qm, Kc, Vc, mask, ctx);

  // out = ctx Wo^T + bo : fp32
  gemm_bt<1><<<dim3(8, 64), 256, 0, stream>>>(ctx, wob, nullptr, nullptr,
                                              nullptr, out, bo, 8192, 1024,
                                              1024);
}